// Round 7
// baseline (308.330 us; speedup 1.0000x reference)
//
#include <hip/hip_runtime.h>
#include <hip/hip_bf16.h>
#include <math.h>

// Problem constants
#define B_   4
#define N_   2048
#define DIM_ 1024
#define H_   16
#define DH_  64
#define E3_  3072   // 3*H*DH

typedef __attribute__((ext_vector_type(8)))  short s8v;   // 8 bf16 (4 VGPRs)
typedef __attribute__((ext_vector_type(4)))  float f4v;   // 16x16 MFMA accumulator
typedef __attribute__((ext_vector_type(16))) float f16v;  // 32x32 MFMA accumulator

// fast fp32->bf16: round-half-up (adds 0.5 ulp then truncate). 2 VALU ops.
__device__ __forceinline__ unsigned short f2bf_fast(float f) {
    return (unsigned short)((__builtin_bit_cast(unsigned int, f) + 0x8000u) >> 16);
}
// pack two fp32 -> two bf16 in one u32 via v_perm_b32 (3 VALU ops total)
__device__ __forceinline__ unsigned int pkbf(float a, float b) {
    unsigned int ua = __builtin_bit_cast(unsigned int, a) + 0x8000u;
    unsigned int ub = __builtin_bit_cast(unsigned int, b) + 0x8000u;
    return __builtin_amdgcn_perm(ub, ua, 0x07060302);
}
// single-instruction pack: dst.lo = bf16(a), dst.hi = bf16(b)  (RNE)
__device__ __forceinline__ unsigned int cvtpk(float a, float b) {
    unsigned int r;
    asm("v_cvt_pk_bf16_f32 %0, %1, %2" : "=v"(r) : "v"(a), "v"(b));
    return r;
}
// v_permlane32_swap_b32: after execution
//   a' = [a(lanes 0:31) | b(lanes 0:31)],  b' = [a(lanes 32:63) | b(lanes 32:63)]
__device__ __forceinline__ uint2 pl32(unsigned int a, unsigned int b) {
    asm volatile("v_permlane32_swap_b32 %0, %1" : "+v"(a), "+v"(b));
    return make_uint2(a, b);
}

// async global->LDS, 16 B per lane; LDS dest = wave-uniform base + lane*16
__device__ __forceinline__ void gload_lds16(const void* g, void* l) {
    __builtin_amdgcn_global_load_lds(
        (const __attribute__((address_space(1))) unsigned int*)(uintptr_t)g,
        (__attribute__((address_space(3))) unsigned int*)(uintptr_t)l,
        16, 0, 0);
}

// ---------------------------------------------------------------------------
// fp32 -> bf16 convert (perm-packed)
// ---------------------------------------------------------------------------
__global__ __launch_bounds__(256) void cvt_bf16(
    const float* __restrict__ in, unsigned short* __restrict__ out, int n)
{
    const int i = (blockIdx.x * 256 + threadIdx.x) * 4;
    if (i < n) {
        float4 v = *(const float4*)(in + i);
        uint2 pk;
        pk.x = pkbf(v.x, v.y);
        pk.y = pkbf(v.z, v.w);
        *(uint2*)(out + i) = pk;
    }
}

// ---------------------------------------------------------------------------
// QKV projection GEMM v2 (unchanged from round 4; see comments there)
// ---------------------------------------------------------------------------
__global__ __launch_bounds__(512, 1) void gemm_qkv(
    const unsigned short* __restrict__ A,    // x_bf [8192][1024]
    const unsigned short* __restrict__ Bw,   // wqkv_bf [3072][1024]
    unsigned short* __restrict__ Cb,         // qkv bf16 [8192][3072]
    unsigned short* __restrict__ Vt)         // [B*H][64][2048]
{
    __shared__ unsigned short Ls[2][28672];

    const int tid  = threadIdx.x;
    const int w    = tid >> 6;          // 0..7
    const int lane = tid & 63;
    const int quad = lane >> 4;
    const int l15  = lane & 15;
    const int wm   = w & 1;             // M half (128 rows)
    const int wn   = w >> 1;            // N quarter (48 cols)

    const int lin = blockIdx.y * 16 + blockIdx.x;
    const int swz = (lin & 7) * 64 + (lin >> 3);
    const int m0  = (swz >> 4) * 256;
    const int n0  = (swz & 15) * 192;

    const int r8  = lane >> 3;              // 0..7
    const int chk = (lane & 7) ^ r8;        // pre-swizzled source chunk

    f4v acc[8][3];
    #pragma unroll
    for (int i = 0; i < 8; i++)
        #pragma unroll
        for (int j = 0; j < 3; j++) acc[i][j] = (f4v){0.f, 0.f, 0.f, 0.f};

    #pragma unroll
    for (int j = 0; j < 7; j++) {
        const int u = w * 7 + j;
        const unsigned short* src = (u < 32)
            ? A  + (size_t)(m0 + u * 8 + r8) * 1024 + chk * 8
            : Bw + (size_t)(n0 + (u - 32) * 8 + r8) * 1024 + chk * 8;
        gload_lds16(src, &Ls[0][u * 512]);
    }
    __syncthreads();

    for (int t = 0; t < 16; t++) {
        const int cur = t & 1;

        if (t + 1 < 16) {
            const int k0 = (t + 1) * 64;
            #pragma unroll
            for (int j = 0; j < 7; j++) {
                const int u = w * 7 + j;
                const unsigned short* src = (u < 32)
                    ? A  + (size_t)(m0 + u * 8 + r8) * 1024 + k0 + chk * 8
                    : Bw + (size_t)(n0 + (u - 32) * 8 + r8) * 1024 + k0 + chk * 8;
                gload_lds16(src, &Ls[cur ^ 1][u * 512]);
            }
        }

        #pragma unroll
        for (int s = 0; s < 2; s++) {
            s8v af[8], bf[3];
            #pragma unroll
            for (int ms = 0; ms < 8; ms++) {
                const int row = wm * 128 + ms * 16 + l15;
                af[ms] = *(const s8v*)&Ls[cur][row * 64 + (((s * 4 + quad) ^ (l15 & 7)) * 8)];
            }
            #pragma unroll
            for (int ns = 0; ns < 3; ns++) {
                const int row = 256 + wn * 48 + ns * 16 + l15;
                bf[ns] = *(const s8v*)&Ls[cur][row * 64 + (((s * 4 + quad) ^ (l15 & 7)) * 8)];
            }
            __builtin_amdgcn_s_setprio(1);
            #pragma unroll
            for (int ms = 0; ms < 8; ms++)
                #pragma unroll
                for (int ns = 0; ns < 3; ns++)
                    acc[ms][ns] = __builtin_amdgcn_mfma_f32_16x16x32_bf16(
                        af[ms], bf[ns], acc[ms][ns], 0, 0, 0);
            __builtin_amdgcn_s_setprio(0);
        }

        __syncthreads();
    }

    #pragma unroll
    for (int ns = 0; ns < 3; ns++) {
        const int colb = n0 + wn * 48 + ns * 16;   // wave-uniform, 16-aligned
        if (colb < 2048) {
            const float mul = (colb < 1024) ? 0.18033688011112042f : 1.0f;
            #pragma unroll
            for (int ms = 0; ms < 8; ms++)
                #pragma unroll
                for (int r = 0; r < 4; r++) {
                    const int row = m0 + wm * 128 + ms * 16 + quad * 4 + r;
                    Cb[(size_t)row * E3_ + colb + l15] = f2bf_fast(acc[ms][ns][r] * mul);
                }
        } else {
            const int e = colb + l15 - 2048;
            const int hh = e >> 6, d = e & 63;       // wave-uniform head
            #pragma unroll
            for (int ms = 0; ms < 8; ms++) {
                const int row = m0 + wm * 128 + ms * 16 + quad * 4;  // 4-aligned
                const int bb = row >> 11, nn = row & 2047;
                uint2 pk;
                pk.x = pkbf(acc[ms][ns][0], acc[ms][ns][1]);
                pk.y = pkbf(acc[ms][ns][2], acc[ms][ns][3]);
                *(uint2*)&Vt[(((size_t)bb * 16 + hh) * 64 + d) * 2048 + nn] = pk;
            }
        }
    }
}

// ---------------------------------------------------------------------------
// out projection GEMM (unchanged from round 4)
// ---------------------------------------------------------------------------
__global__ __launch_bounds__(256) void gemm_out(
    const unsigned short* __restrict__ A,
    const unsigned short* __restrict__ Bw,
    const float* __restrict__ bias,
    float* __restrict__ Cf,
    int M, int Nc, int K)
{
    __shared__ unsigned short As[128 * 32];
    __shared__ unsigned short Bs[128 * 32];

    const int tid  = threadIdx.x;
    const int w    = tid >> 6;
    const int lane = tid & 63;
    const int quad = lane >> 4;
    const int l15  = lane & 15;
    const int wm   = w & 1, wn = w >> 1;

    const int nwx = gridDim.x;
    const int lin = blockIdx.y * nwx + blockIdx.x;
    const int cpx = (nwx * gridDim.y) >> 3;       // nwg/8 (nwg%8==0)
    const int swz = (lin & 7) * cpx + (lin >> 3);
    const int m0  = (swz / nwx) * 128, n0 = (swz % nwx) * 128;

    const int srow = lane >> 2;        // 0..15
    const int sch  = (lane & 3) * 8;   // k element offset 0,8,16,24

    f4v acc[4][4];
    #pragma unroll
    for (int i = 0; i < 4; i++)
        #pragma unroll
        for (int j = 0; j < 4; j++) acc[i][j] = (f4v){0.f, 0.f, 0.f, 0.f};

    for (int k0 = 0; k0 < K; k0 += 32) {
        __syncthreads();
        #pragma unroll
        for (int i = 0; i < 2; i++) {
            const int rbase = w * 32 + i * 16;
            gload_lds16(A  + (size_t)(m0 + rbase + srow) * K + k0 + sch,
                        &As[rbase * 32]);
            gload_lds16(Bw + (size_t)(n0 + rbase + srow) * K + k0 + sch,
                        &Bs[rbase * 32]);
        }
        __syncthreads();

        s8v af[4], bf[4];
        #pragma unroll
        for (int i = 0; i < 4; i++) {
            af[i] = *(const s8v*)&As[(wm * 64 + i * 16 + l15) * 32 + quad * 8];
            bf[i] = *(const s8v*)&Bs[(wn * 64 + i * 16 + l15) * 32 + quad * 8];
        }
        #pragma unroll
        for (int ms = 0; ms < 4; ms++)
            #pragma unroll
            for (int ns = 0; ns < 4; ns++)
                acc[ms][ns] = __builtin_amdgcn_mfma_f32_16x16x32_bf16(
                    af[ms], bf[ns], acc[ms][ns], 0, 0, 0);
    }

    #pragma unroll
    for (int ns = 0; ns < 4; ns++) {
        const float bz = bias[n0 + wn * 64 + ns * 16 + l15];
        #pragma unroll
        for (int ms = 0; ms < 4; ms++)
            #pragma unroll
            for (int r = 0; r < 4; r++) {
                const int row = m0 + wm * 64 + ms * 16 + quad * 4 + r;
                Cf[(size_t)row * Nc + n0 + wn * 64 + ns * 16 + l15] =
                    acc[ms][ns][r] + bz;
            }
    }
}

// ---------------------------------------------------------------------------
// MFMA flash attention v10: NO LDS, NO BARRIERS — direct-from-L2 fragments.
// v9 post-mortem: no pipe saturated (MFMA 42 + VALU 35 + LDS 31), 2
// waves/SIMD (structural cap at 64 q/wave), so the 32 per-tile full-block
// barriers + per-wave serial chain dominate -> sync/dependency-bound.
// v10 deletes the sharing that forced the sync:
// - ak (K) and bv (V) fragments load DIRECTLY from global. Lane pairs
//   (l, l+32) cover contiguous 32B; one tile's K reads touch exactly its
//   64 x 128B L2 lines (d-range = 128B), same for V (key-range = 128B):
//   zero over-fetch, L2-resident (FETCH 24.6MB), XCD-local (same-bh
//   blocks pinned to one XCD; ~2.3 of 4.3 TB/s per-XCD L2 BW).
// - zero __syncthreads: waves fully independent, each hides its own L2
//   latency (~200cy under 16 issued-ahead loads; ak issued before bv so
//   QK waits at vmcnt(4) while bv stays in flight under QK+exp2).
// - math, P-redistribute (cvt_pk+permlane32_swap), lc-MFMA denominator,
//   epilogue: byte-identical to v9 (passed).
// 256 thr = 4 waves x 64 q; grid (8,64)=512 blocks = 2/CU = 8 waves/CU.
// qkv bf16 [m][3072] (Q pre-scaled by 0.125*log2e); vT[b*16+h][d][n] bf16.
// ---------------------------------------------------------------------------
__global__ __launch_bounds__(256, 2) void attn_mfma(
    const unsigned short* __restrict__ qkv,
    const unsigned short* __restrict__ vT,
    unsigned short* __restrict__ ao)
{
    const int tid  = threadIdx.x;
    const int w    = tid >> 6;          // 0..3
    const int lane = tid & 63;
    const int l31  = lane & 31;
    const int hi5  = lane >> 5;         // 0/1
    const int h8   = hi5 * 8;

    // XCD mapping: grid (8,64) = 512 blocks; all 8 q-chunks of one bh on
    // one XCD (K/V L2-local).
    const int lin = blockIdx.y * 8 + blockIdx.x;
    const int j0  = (lin & 7) * 64 + (lin >> 3);
    const int bx  = j0 & 7;             // q-chunk 0..7
    const int bh  = j0 >> 3;
    const int b   = bh >> 4;
    const int h   = bh & 15;
    const int qb  = bx * 256 + w * 64;  // 64 q-rows per wave

    const unsigned short* qp  = qkv + (size_t)b * N_ * E3_ + (size_t)h * DH_;
    const unsigned short* kp  = qp + 1024;
    const unsigned short* vtp = vT + (size_t)bh * 64 * 2048;

    // Q B-fragments straight from global (one-time): B[k=d][col=qrow]
    s8v bq[2][4];
    #pragma unroll
    for (int sub = 0; sub < 2; sub++) {
        const unsigned short* qrow = qp + (size_t)(qb + sub * 32 + l31) * E3_;
        #pragma unroll
        for (int ks = 0; ks < 4; ks++)
            bq[sub][ks] = *(const s8v*)(qrow + ks * 16 + h8);
    }

    // ones B-fragment (bf16 1.0) for row-sum MFMA
    s8v ones;
    #pragma unroll
    for (int i = 0; i < 8; i++) ones[i] = (short)0x3F80;

    const f16v fzero = {0.f,0.f,0.f,0.f,0.f,0.f,0.f,0.f,
                        0.f,0.f,0.f,0.f,0.f,0.f,0.f,0.f};
    f16v o[2][2];      // [q-subtile][d-tile]
    o[0][0] = fzero; o[0][1] = fzero; o[1][0] = fzero; o[1][1] = fzero;
    f16v lc[2];        // row-sums, layout-matched to o
    lc[0] = fzero; lc[1] = fzero;

    for (int kt = 0; kt < N_ / 64; kt++) {
        const int kb = kt * 64;

        #pragma unroll
        for (int ksub = 0; ksub < 2; ksub++) {
            // K A-fragments direct from global: A[row=key][k=d]
            // (issued FIRST so QK's wait leaves bv in flight)
            const unsigned short* krow =
                kp + (size_t)(kb + ksub * 32 + l31) * E3_;
            s8v ak[4];
            #pragma unroll
            for (int ks = 0; ks < 4; ks++)
                ak[ks] = *(const s8v*)(krow + ks * 16 + h8);

            // V B-fragments direct from global: B[k=key][col=d]
            s8v bv[2][2];   // [j][dtile]
            #pragma unroll
            for (int j = 0; j < 2; j++)
                #pragma unroll
                for (int dt = 0; dt < 2; dt++)
                    bv[j][dt] = *(const s8v*)(vtp
                        + (size_t)(dt * 32 + l31) * 2048
                        + kb + (ksub * 2 + j) * 16 + h8);

            // S^T -> exp2 -> in-register P A-fragments, for both q-subtiles
            s8v pa[2][2];   // [sub][j]
            #pragma unroll
            for (int sub = 0; sub < 2; sub++) {
                f16v st = fzero;
                __builtin_amdgcn_s_setprio(1);
                st = __builtin_amdgcn_mfma_f32_32x32x16_bf16(ak[0], bq[sub][0], st, 0, 0, 0);
                st = __builtin_amdgcn_mfma_f32_32x32x16_bf16(ak[1], bq[sub][1], st, 0, 0, 0);
                st = __builtin_amdgcn_mfma_f32_32x32x16_bf16(ak[2], bq[sub][2], st, 0, 0, 0);
                st = __builtin_amdgcn_mfma_f32_32x32x16_bf16(ak[3], bq[sub][3], st, 0, 0, 0);
                __builtin_amdgcn_s_setprio(0);

                float pe[16];
                #pragma unroll
                for (int i = 0; i < 16; i++)
                    pe[i] = __builtin_amdgcn_exp2f(st[i]);

                // pack pairs, swap halves: lane gets its q-row's keys
                union { s8v v; unsigned int u[4]; } f0, f1;
                uint2 r;
                r = pl32(cvtpk(pe[0],  pe[1]),  cvtpk(pe[4],  pe[5]));
                f0.u[0] = r.x; f0.u[2] = r.y;
                r = pl32(cvtpk(pe[2],  pe[3]),  cvtpk(pe[6],  pe[7]));
                f0.u[1] = r.x; f0.u[3] = r.y;
                r = pl32(cvtpk(pe[8],  pe[9]),  cvtpk(pe[12], pe[13]));
                f1.u[0] = r.x; f1.u[2] = r.y;
                r = pl32(cvtpk(pe[10], pe[11]), cvtpk(pe[14], pe[15]));
                f1.u[1] = r.x; f1.u[3] = r.y;
                pa[sub][0] = f0.v;   // keys ksub*32 + 0..15
                pa[sub][1] = f1.v;   // keys ksub*32 + 16..31
            }

            // ---- O += P V ; l += P @ ones ----
            #pragma unroll
            for (int j = 0; j < 2; j++) {
                __builtin_amdgcn_s_setprio(1);
                o[0][0] = __builtin_amdgcn_mfma_f32_32x32x16_bf16(pa[0][j], bv[j][0], o[0][0], 0, 0, 0);
                o[0][1] = __builtin_amdgcn_mfma_f32_32x32x16_bf16(pa[0][j], bv[j][1], o[0][1], 0, 0, 0);
                o[1][0] = __builtin_amdgcn_mfma_f32_32x32x16_bf16(pa[1][j], bv[j][0], o[1][0], 0, 0, 0);
                o[1][1] = __builtin_amdgcn_mfma_f32_32x32x16_bf16(pa[1][j], bv[j][1], o[1][1], 0, 0, 0);
                lc[0]   = __builtin_amdgcn_mfma_f32_32x32x16_bf16(pa[0][j], ones, lc[0], 0, 0, 0);
                lc[1]   = __builtin_amdgcn_mfma_f32_32x32x16_bf16(pa[1][j], ones, lc[1], 0, 0, 0);
                __builtin_amdgcn_s_setprio(0);
            }
        }
    }

    // ---- normalize + write ao bf16 [m][1024]; lc layout == o layout ----
    #pragma unroll
    for (int sub = 0; sub < 2; sub++) {
        float inv[16];
        #pragma unroll
        for (int r = 0; r < 16; r++) inv[r] = 1.f / lc[sub][r];
        #pragma unroll
        for (int r = 0; r < 16; r++) {
            const int crow = (r & 3) + 8 * (r >> 2) + 4 * hi5;
            const int qrow = qb + sub * 32 + crow;
            const size_t base = ((size_t)b * N_ + qrow) * (H_ * DH_) + h * DH_;
            ao[base + l31]      = f2bf_fast(o[sub][0][r] * inv[r]);
            ao[base + 32 + l31] = f2bf_fast(o[sub][1][r] * inv[r]);
        }
    }
}

// ---------------------------------------------------------------------------
// Launch
// ---------------------------------------------------------------------------
extern "C" void kernel_launch(void* const* d_in, const int* in_sizes, int n_in,
                              void* d_out, int out_size, void* d_ws, size_t ws_size,
                              hipStream_t stream) {
    const float* x     = (const float*)d_in[0];   // [B,N,DIM]
    const float* w_qkv = (const float*)d_in[1];   // [3072, 1024]
    const float* w_out = (const float*)d_in[2];   // [1024, 1024]
    const float* b_out = (const float*)d_in[3];   // [1024]
    float* out = (float*)d_out;                   // [B,N,DIM] fp32

    char* ws = (char*)d_ws;
    unsigned short* x_bf    = (unsigned short*)(ws);                        // 16 MB
    unsigned short* wqkv_bf = (unsigned short*)(ws + (((size_t)16) << 20)); //  6 MB
    unsigned short* wout_bf = (unsigned short*)(ws + (((size_t)22) << 20)); //  2 MB
    unsigned short* qkv_bf  = (unsigned short*)(ws + (((size_t)24) << 20)); // 48 MB
    unsigned short* vT      = (unsigned short*)(ws + (((size_t)72) << 20)); // 16 MB
    unsigned short* ao_bf   = (unsigned short*)(ws + (((size_t)88) << 20)); // 16 MB

    const int M = B_ * N_;   // 8192

    // 0) input conversions fp32 -> bf16
    cvt_bf16<<<(M * DIM_) / 1024, 256, 0, stream>>>(x, x_bf, M * DIM_);
    cvt_bf16<<<(E3_ * DIM_) / 1024, 256, 0, stream>>>(w_qkv, wqkv_bf, E3_ * DIM_);
    cvt_bf16<<<(DIM_ * DIM_) / 1024, 256, 0, stream>>>(w_out, wout_bf, DIM_ * DIM_);

    // 1) QKV projection v2: 256x192x64 tiles, dbuf+prefetch, swizzled LDS
    {
        dim3 grid(E3_ / 192, M / 256);   // (16, 32) = 512 blocks
        gemm_qkv<<<grid, 512, 0, stream>>>(x_bf, wqkv_bf, qkv_bf, vT);
    }
    // 2) attention v10: no-LDS/no-barrier, direct-L2 fragments,
    //    4 waves x 64 q, 512 blocks
    {
        dim3 grid(N_ / 256, B_ * H_);    // (8, 64) = 512 blocks
        attn_mfma<<<grid, 256, 0, stream>>>(qkv_bf, vT, ao_bf);
    }
    // 3) out projection (bf16 MFMA, fp32 + bias out)
    {
        dim3 grid(DIM_ / 128, M / 128);  // (8, 64) = 512 blocks (%8==0)
        gemm_out<<<grid, 256, 0, stream>>>(ao_bf, wout_bf, b_out,
                                           out, M, DIM_, DIM_);
    }
    (void)in_sizes; (void)n_in; (void)out_size; (void)ws_size;
}

// Round 8
// 273.759 us; speedup vs baseline: 1.1263x; 1.1263x over previous
//
#include <hip/hip_runtime.h>
#include <hip/hip_bf16.h>
#include <math.h>

// Problem constants
#define B_   4
#define N_   2048
#define DIM_ 1024
#define H_   16
#define DH_  64
#define E3_  3072   // 3*H*DH

typedef __attribute__((ext_vector_type(8)))  short s8v;   // 8 bf16 (4 VGPRs)
typedef __attribute__((ext_vector_type(4)))  float f4v;   // 16x16 MFMA accumulator
typedef __attribute__((ext_vector_type(16))) float f16v;  // 32x32 MFMA accumulator

// fast fp32->bf16: round-half-up (adds 0.5 ulp then truncate). 2 VALU ops.
__device__ __forceinline__ unsigned short f2bf_fast(float f) {
    return (unsigned short)((__builtin_bit_cast(unsigned int, f) + 0x8000u) >> 16);
}
// pack two fp32 -> two bf16 in one u32 via v_perm_b32 (3 VALU ops total)
__device__ __forceinline__ unsigned int pkbf(float a, float b) {
    unsigned int ua = __builtin_bit_cast(unsigned int, a) + 0x8000u;
    unsigned int ub = __builtin_bit_cast(unsigned int, b) + 0x8000u;
    return __builtin_amdgcn_perm(ub, ua, 0x07060302);
}
// single-instruction pack: dst.lo = bf16(a), dst.hi = bf16(b)  (RNE)
__device__ __forceinline__ unsigned int cvtpk(float a, float b) {
    unsigned int r;
    asm("v_cvt_pk_bf16_f32 %0, %1, %2" : "=v"(r) : "v"(a), "v"(b));
    return r;
}
// v_permlane32_swap_b32: after execution
//   a' = [a(lanes 0:31) | b(lanes 0:31)],  b' = [a(lanes 32:63) | b(lanes 32:63)]
__device__ __forceinline__ uint2 pl32(unsigned int a, unsigned int b) {
    asm volatile("v_permlane32_swap_b32 %0, %1" : "+v"(a), "+v"(b));
    return make_uint2(a, b);
}

// async global->LDS, 16 B per lane; LDS dest = wave-uniform base + lane*16
__device__ __forceinline__ void gload_lds16(const void* g, void* l) {
    __builtin_amdgcn_global_load_lds(
        (const __attribute__((address_space(1))) unsigned int*)(uintptr_t)g,
        (__attribute__((address_space(3))) unsigned int*)(uintptr_t)l,
        16, 0, 0);
}

// ---------------------------------------------------------------------------
// fp32 -> bf16 convert (perm-packed)
// ---------------------------------------------------------------------------
__global__ __launch_bounds__(256) void cvt_bf16(
    const float* __restrict__ in, unsigned short* __restrict__ out, int n)
{
    const int i = (blockIdx.x * 256 + threadIdx.x) * 4;
    if (i < n) {
        float4 v = *(const float4*)(in + i);
        uint2 pk;
        pk.x = pkbf(v.x, v.y);
        pk.y = pkbf(v.z, v.w);
        *(uint2*)(out + i) = pk;
    }
}

// ---------------------------------------------------------------------------
// QKV projection GEMM v3: qkv[8192][3072] = x[8192][1024] @ w_qkv^T.
// v2 (BM256xBN192, 512thr, 112KB LDS) was structurally capped at 1 block/CU
// (8 waves/CU, full-block barrier per K-step = the v9 convoy disease).
// v3 re-tiles the SAME logic to BM=128 x BN=192 x BK=64, 256 thr = 4 waves
// (2M x 2N, wave tile 64x96 = 4x6 16x16x32 MFMAs x 2 k-steps), 80 KB LDS
// -> 2 blocks/CU (160KB exactly), grid (16,64) = 1024 blocks.
// Per wave-step: 20 b128 reads (160cy) vs 48 MFMA (233cy) -> MFMA-led.
// Same both-sides swizzle (chunk ^= row&7); all row bases %16==0 so
// row&7 == l15&7 on the read side.
// Q-third pre-scaled by 0.125*log2(e); V-third redirected to vT[b,h,d,n].
// ---------------------------------------------------------------------------
__global__ __launch_bounds__(256, 2) void gemm_qkv(
    const unsigned short* __restrict__ A,    // x_bf [8192][1024]
    const unsigned short* __restrict__ Bw,   // wqkv_bf [3072][1024]
    unsigned short* __restrict__ Cb,         // qkv bf16 [8192][3072]
    unsigned short* __restrict__ Vt)         // [B*H][64][2048]
{
    // [buf][(128 A-rows + 192 B-rows) * 64 el] = 2 x 40 KB
    __shared__ unsigned short Ls[2][20480];

    const int tid  = threadIdx.x;
    const int w    = tid >> 6;          // 0..3
    const int lane = tid & 63;
    const int quad = lane >> 4;
    const int l15  = lane & 15;
    const int wm   = w & 1;             // M half (64 rows)
    const int wn   = w >> 1;            // N half (96 cols)

    // XCD-chunked swizzle: 1024 blocks -> 128 per XCD (8 full A-panel rows)
    const int lin = blockIdx.y * 16 + blockIdx.x;
    const int swz = (lin & 7) * 128 + (lin >> 3);
    const int m0  = (swz >> 4) * 128;
    const int n0  = (swz & 15) * 192;

    // staging: 40 units of 1 KB (8 rows x 64 el); wave w stages units
    // w*10..w*10+9. Lane: row = unit*8 + (lane>>3), source chunk pre-swizzled.
    const int r8  = lane >> 3;              // 0..7
    const int chk = (lane & 7) ^ r8;        // pre-swizzled source chunk

    f4v acc[4][6];
    #pragma unroll
    for (int i = 0; i < 4; i++)
        #pragma unroll
        for (int j = 0; j < 6; j++) acc[i][j] = (f4v){0.f, 0.f, 0.f, 0.f};

    // ---- prologue: stage tile 0 into buffer 0 ----
    #pragma unroll
    for (int j = 0; j < 10; j++) {
        const int u = w * 10 + j;
        const unsigned short* src = (u < 16)
            ? A  + (size_t)(m0 + u * 8 + r8) * 1024 + chk * 8
            : Bw + (size_t)(n0 + (u - 16) * 8 + r8) * 1024 + chk * 8;
        gload_lds16(src, &Ls[0][u * 512]);
    }
    __syncthreads();

    for (int t = 0; t < 16; t++) {
        const int cur = t & 1;

        // ---- issue next tile's DMA first (latency hidden by compute) ----
        if (t + 1 < 16) {
            const int k0 = (t + 1) * 64;
            #pragma unroll
            for (int j = 0; j < 10; j++) {
                const int u = w * 10 + j;
                const unsigned short* src = (u < 16)
                    ? A  + (size_t)(m0 + u * 8 + r8) * 1024 + k0 + chk * 8
                    : Bw + (size_t)(n0 + (u - 16) * 8 + r8) * 1024 + k0 + chk * 8;
                gload_lds16(src, &Ls[cur ^ 1][u * 512]);
            }
        }

        // ---- compute on current buffer: 2 k-steps x (4x6) MFMAs ----
        #pragma unroll
        for (int s = 0; s < 2; s++) {
            s8v af[4], bf[6];
            #pragma unroll
            for (int ms = 0; ms < 4; ms++) {
                const int row = wm * 64 + ms * 16 + l15;
                af[ms] = *(const s8v*)&Ls[cur][row * 64 + (((s * 4 + quad) ^ (l15 & 7)) * 8)];
            }
            #pragma unroll
            for (int ns = 0; ns < 6; ns++) {
                const int row = 128 + wn * 96 + ns * 16 + l15;
                bf[ns] = *(const s8v*)&Ls[cur][row * 64 + (((s * 4 + quad) ^ (l15 & 7)) * 8)];
            }
            __builtin_amdgcn_s_setprio(1);
            #pragma unroll
            for (int ms = 0; ms < 4; ms++)
                #pragma unroll
                for (int ns = 0; ns < 6; ns++)
                    acc[ms][ns] = __builtin_amdgcn_mfma_f32_16x16x32_bf16(
                        af[ms], bf[ns], acc[ms][ns], 0, 0, 0);
            __builtin_amdgcn_s_setprio(0);
        }

        __syncthreads();
    }

    // ---- epilogue: C/D layout col = l15, row = quad*4 + r ----
    #pragma unroll
    for (int ns = 0; ns < 6; ns++) {
        const int colb = n0 + wn * 96 + ns * 16;   // wave-uniform, 16-aligned
        if (colb < 2048) {
            // fold softmax scale*log2(e) into Q columns
            const float mul = (colb < 1024) ? 0.18033688011112042f : 1.0f;
            #pragma unroll
            for (int ms = 0; ms < 4; ms++)
                #pragma unroll
                for (int r = 0; r < 4; r++) {
                    const int row = m0 + wm * 64 + ms * 16 + quad * 4 + r;
                    Cb[(size_t)row * E3_ + colb + l15] = f2bf_fast(acc[ms][ns][r] * mul);
                }
        } else {
            const int e = colb + l15 - 2048;
            const int hh = e >> 6, d = e & 63;       // wave-uniform head
            #pragma unroll
            for (int ms = 0; ms < 4; ms++) {
                const int row = m0 + wm * 64 + ms * 16 + quad * 4;   // 4-aligned
                const int bb = row >> 11, nn = row & 2047;
                uint2 pk;
                pk.x = pkbf(acc[ms][ns][0], acc[ms][ns][1]);
                pk.y = pkbf(acc[ms][ns][2], acc[ms][ns][3]);
                *(uint2*)&Vt[(((size_t)bb * 16 + hh) * 64 + d) * 2048 + nn] = pk;
            }
        }
    }
}

// ---------------------------------------------------------------------------
// out projection GEMM (unchanged from round 4)
// ---------------------------------------------------------------------------
__global__ __launch_bounds__(256) void gemm_out(
    const unsigned short* __restrict__ A,
    const unsigned short* __restrict__ Bw,
    const float* __restrict__ bias,
    float* __restrict__ Cf,
    int M, int Nc, int K)
{
    __shared__ unsigned short As[128 * 32];
    __shared__ unsigned short Bs[128 * 32];

    const int tid  = threadIdx.x;
    const int w    = tid >> 6;
    const int lane = tid & 63;
    const int quad = lane >> 4;
    const int l15  = lane & 15;
    const int wm   = w & 1, wn = w >> 1;

    const int nwx = gridDim.x;
    const int lin = blockIdx.y * nwx + blockIdx.x;
    const int cpx = (nwx * gridDim.y) >> 3;       // nwg/8 (nwg%8==0)
    const int swz = (lin & 7) * cpx + (lin >> 3);
    const int m0  = (swz / nwx) * 128, n0 = (swz % nwx) * 128;

    const int srow = lane >> 2;        // 0..15
    const int sch  = (lane & 3) * 8;   // k element offset 0,8,16,24

    f4v acc[4][4];
    #pragma unroll
    for (int i = 0; i < 4; i++)
        #pragma unroll
        for (int j = 0; j < 4; j++) acc[i][j] = (f4v){0.f, 0.f, 0.f, 0.f};

    for (int k0 = 0; k0 < K; k0 += 32) {
        __syncthreads();
        #pragma unroll
        for (int i = 0; i < 2; i++) {
            const int rbase = w * 32 + i * 16;
            gload_lds16(A  + (size_t)(m0 + rbase + srow) * K + k0 + sch,
                        &As[rbase * 32]);
            gload_lds16(Bw + (size_t)(n0 + rbase + srow) * K + k0 + sch,
                        &Bs[rbase * 32]);
        }
        __syncthreads();

        s8v af[4], bf[4];
        #pragma unroll
        for (int i = 0; i < 4; i++) {
            af[i] = *(const s8v*)&As[(wm * 64 + i * 16 + l15) * 32 + quad * 8];
            bf[i] = *(const s8v*)&Bs[(wn * 64 + i * 16 + l15) * 32 + quad * 8];
        }
        #pragma unroll
        for (int ms = 0; ms < 4; ms++)
            #pragma unroll
            for (int ns = 0; ns < 4; ns++)
                acc[ms][ns] = __builtin_amdgcn_mfma_f32_16x16x32_bf16(
                    af[ms], bf[ns], acc[ms][ns], 0, 0, 0);
    }

    #pragma unroll
    for (int ns = 0; ns < 4; ns++) {
        const float bz = bias[n0 + wn * 64 + ns * 16 + l15];
        #pragma unroll
        for (int ms = 0; ms < 4; ms++)
            #pragma unroll
            for (int r = 0; r < 4; r++) {
                const int row = m0 + wm * 64 + ms * 16 + quad * 4 + r;
                Cf[(size_t)row * Nc + n0 + wn * 64 + ns * 16 + l15] =
                    acc[ms][ns][r] + bz;
            }
    }
}

// ---------------------------------------------------------------------------
// MFMA flash attention v11: v7's math, re-tiled to 4-wave blocks.
// v10 post-mortem: direct-from-L2 fragments are SCATTER reads (32 distinct
// 128B lines per instr, 32B used each) -> TA/L2-request-bound, 138us. LDS
// staging is what coalesces K/V; it stays. v7 (8w blocks, 2 blk/CU) = 80us
// with MfmaUtil 49 / VALU 44 / nothing saturated -> convoy effect: barriers
// rendezvous 8 waves + vmcnt drain, phase-locking the CU.
// v11: SAME per-wave math as v7 (32 q/wave, QK->exp2/pack->PV, lc-MFMA
// denominator), but 256-thr blocks, grid (16,64) = 1024 blocks = 4
// independent blocks/CU (4 x 32KB = 128KB LDS). Barriers now sync only 4
// waves; 4 out-of-phase tile streams per CU feed the shared MFMA pipe.
// qkv bf16 [m][3072] (Q pre-scaled by 0.125*log2e); vT[b*16+h][d][n] bf16.
// ---------------------------------------------------------------------------
__global__ __launch_bounds__(256, 4) void attn_mfma(
    const unsigned short* __restrict__ qkv,
    const unsigned short* __restrict__ vT,
    unsigned short* __restrict__ ao)
{
    __shared__ __align__(16) unsigned short Ks[2][64][64];   // [buf][key][d] swz
    __shared__ __align__(16) unsigned short Vs[2][64][64];   // [buf][d][key] swz

    const int tid  = threadIdx.x;
    const int w    = tid >> 6;          // 0..3
    const int lane = tid & 63;
    const int l31  = lane & 31;
    const int hi5  = lane >> 5;         // 0/1
    const int h8   = hi5 * 8;

    // XCD mapping: 1024 blocks, 128 per XCD -> 8 consecutive bh per XCD
    const int lin = blockIdx.y * 16 + blockIdx.x;
    const int j0  = (lin & 7) * 128 + (lin >> 3);
    const int bx  = j0 & 15;            // q-chunk 0..15
    const int bh  = j0 >> 4;
    const int b   = bh >> 4;
    const int h   = bh & 15;
    const int qb  = bx * 128 + w * 32;  // 32 q-rows per wave

    const unsigned short* qp  = qkv + (size_t)b * N_ * E3_ + (size_t)h * DH_;
    const unsigned short* kp  = qp + 1024;
    const unsigned short* vtp = vT + (size_t)bh * 64 * 2048;

    // DMA staging: wave w stages rows w*16..w*16+15 of K and V (2 gloads
    // per tensor). LDS dest linear; source chunk pre-swizzled (^= row&7;
    // +8 rows keeps row&7 == drow).
    const int drow = lane >> 3;             // 0..7 within 8-row slice
    const int dchk = (lane & 7) ^ drow;     // pre-swizzled source chunk
    const int grow = w * 16 + drow;

    // Q B-fragments straight from global (one-time): B[k=d][col=qrow]
    s8v bq[4];
    {
        const unsigned short* qrow = qp + (size_t)(qb + l31) * E3_;
        #pragma unroll
        for (int ks = 0; ks < 4; ks++)
            bq[ks] = *(const s8v*)(qrow + ks * 16 + h8);
    }

    // ones B-fragment (bf16 1.0) for row-sum MFMA
    s8v ones;
    #pragma unroll
    for (int i = 0; i < 8; i++) ones[i] = (short)0x3F80;

    const f16v fzero = {0.f,0.f,0.f,0.f,0.f,0.f,0.f,0.f,
                        0.f,0.f,0.f,0.f,0.f,0.f,0.f,0.f};
    f16v o0 = fzero, o1 = fzero;   // d = 0..31 / 32..63
    f16v lc = fzero;               // row-sums, layout-matched to o

    // ---- prologue: DMA tile 0 into buffer 0 ----
    gload_lds16(kp  + (size_t)grow * E3_        + dchk * 8, &Ks[0][w * 16][0]);
    gload_lds16(kp  + (size_t)(grow + 8) * E3_  + dchk * 8, &Ks[0][w * 16 + 8][0]);
    gload_lds16(vtp + (size_t)grow * 2048       + dchk * 8, &Vs[0][w * 16][0]);
    gload_lds16(vtp + (size_t)(grow + 8) * 2048 + dchk * 8, &Vs[0][w * 16 + 8][0]);
    __syncthreads();

    for (int kt = 0; kt < N_ / 64; kt++) {
        const int cur = kt & 1;

        // ---- DMA next tile into back buffer (latency hidden by compute) ----
        if (kt + 1 < N_ / 64) {
            const int kn = (kt + 1) * 64;
            const int nxt = cur ^ 1;
            gload_lds16(kp  + (size_t)(kn + grow) * E3_       + dchk * 8, &Ks[nxt][w * 16][0]);
            gload_lds16(kp  + (size_t)(kn + grow + 8) * E3_   + dchk * 8, &Ks[nxt][w * 16 + 8][0]);
            gload_lds16(vtp + (size_t)grow * 2048       + kn + dchk * 8, &Vs[nxt][w * 16][0]);
            gload_lds16(vtp + (size_t)(grow + 8) * 2048 + kn + dchk * 8, &Vs[nxt][w * 16 + 8][0]);
        }

        #pragma unroll
        for (int ksub = 0; ksub < 2; ksub++) {
            // K A-fragments: A[row=key][k=d], row = ksub*32 + l31
            const int krow = ksub * 32 + l31;
            const int ksw  = (l31 & 7) * 8;     // krow&7 == l31&7
            s8v ak[4];
            #pragma unroll
            for (int ks = 0; ks < 4; ks++)
                ak[ks] = *(const s8v*)&Ks[cur][krow][(ks * 16 + h8) ^ ksw];

            // S^T -> exp2 -> in-register P A-fragments
            f16v st = fzero;
            __builtin_amdgcn_s_setprio(1);
            st = __builtin_amdgcn_mfma_f32_32x32x16_bf16(ak[0], bq[0], st, 0, 0, 0);
            st = __builtin_amdgcn_mfma_f32_32x32x16_bf16(ak[1], bq[1], st, 0, 0, 0);
            st = __builtin_amdgcn_mfma_f32_32x32x16_bf16(ak[2], bq[2], st, 0, 0, 0);
            st = __builtin_amdgcn_mfma_f32_32x32x16_bf16(ak[3], bq[3], st, 0, 0, 0);
            __builtin_amdgcn_s_setprio(0);

            float pe[16];
            #pragma unroll
            for (int i = 0; i < 16; i++)
                pe[i] = __builtin_amdgcn_exp2f(st[i]);

            // pack pairs, swap halves: lane gets its q-row's keys
            s8v pa[2];
            {
                union { s8v v; unsigned int u[4]; } f0, f1;
                uint2 r;
                r = pl32(cvtpk(pe[0],  pe[1]),  cvtpk(pe[4],  pe[5]));
                f0.u[0] = r.x; f0.u[2] = r.y;
                r = pl32(cvtpk(pe[2],  pe[3]),  cvtpk(pe[6],  pe[7]));
                f0.u[1] = r.x; f0.u[3] = r.y;
                r = pl32(cvtpk(pe[8],  pe[9]),  cvtpk(pe[12], pe[13]));
                f1.u[0] = r.x; f1.u[2] = r.y;
                r = pl32(cvtpk(pe[10], pe[11]), cvtpk(pe[14], pe[15]));
                f1.u[1] = r.x; f1.u[3] = r.y;
                pa[0] = f0.v;   // keys ksub*32 + 0..15
                pa[1] = f1.v;   // keys ksub*32 + 16..31
            }

            // ---- O += P V ; l += P @ ones ----
            #pragma unroll
            for (int j = 0; j < 2; j++) {
                const int kbase = (ksub * 2 + j) * 16 + h8;
                const int vsw   = (l31 & 7) * 8;
                s8v bv0 = *(const s8v*)&Vs[cur][l31     ][kbase ^ vsw];
                s8v bv1 = *(const s8v*)&Vs[cur][32 + l31][kbase ^ vsw];
                __builtin_amdgcn_s_setprio(1);
                o0 = __builtin_amdgcn_mfma_f32_32x32x16_bf16(pa[j], bv0, o0, 0, 0, 0);
                o1 = __builtin_amdgcn_mfma_f32_32x32x16_bf16(pa[j], bv1, o1, 0, 0, 0);
                lc = __builtin_amdgcn_mfma_f32_32x32x16_bf16(pa[j], ones, lc, 0, 0, 0);
                __builtin_amdgcn_s_setprio(0);
            }
        }

        __syncthreads();
    }

    // ---- normalize + write ao bf16 [m][1024]; lc layout == o layout ----
    {
        float inv[16];
        #pragma unroll
        for (int r = 0; r < 16; r++) inv[r] = 1.f / lc[r];
        #pragma unroll
        for (int r = 0; r < 16; r++) {
            const int qrow = qb + (r & 3) + 8 * (r >> 2) + 4 * hi5;
            const size_t base = ((size_t)b * N_ + qrow) * (H_ * DH_) + h * DH_;
            ao[base + l31]      = f2bf_fast(o0[r] * inv[r]);
            ao[base + 32 + l31] = f2bf_fast(o1[r] * inv[r]);
        }
    }
}

// ---------------------------------------------------------------------------
// Launch
// ---------------------------------------------------------------------------
extern "C" void kernel_launch(void* const* d_in, const int* in_sizes, int n_in,
                              void* d_out, int out_size, void* d_ws, size_t ws_size,
                              hipStream_t stream) {
    const float* x     = (const float*)d_in[0];   // [B,N,DIM]
    const float* w_qkv = (const float*)d_in[1];   // [3072, 1024]
    const float* w_out = (const float*)d_in[2];   // [1024, 1024]
    const float* b_out = (const float*)d_in[3];   // [1024]
    float* out = (float*)d_out;                   // [B,N,DIM] fp32

    char* ws = (char*)d_ws;
    unsigned short* x_bf    = (unsigned short*)(ws);                        // 16 MB
    unsigned short* wqkv_bf = (unsigned short*)(ws + (((size_t)16) << 20)); //  6 MB
    unsigned short* wout_bf = (unsigned short*)(ws + (((size_t)22) << 20)); //  2 MB
    unsigned short* qkv_bf  = (unsigned short*)(ws + (((size_t)24) << 20)); // 48 MB
    unsigned short* vT      = (unsigned short*)(ws + (((size_t)72) << 20)); // 16 MB
    unsigned short* ao_bf   = (unsigned short*)(ws + (((size_t)88) << 20)); // 16 MB

    const int M = B_ * N_;   // 8192

    // 0) input conversions fp32 -> bf16
    cvt_bf16<<<(M * DIM_) / 1024, 256, 0, stream>>>(x, x_bf, M * DIM_);
    cvt_bf16<<<(E3_ * DIM_) / 1024, 256, 0, stream>>>(w_qkv, wqkv_bf, E3_ * DIM_);
    cvt_bf16<<<(DIM_ * DIM_) / 1024, 256, 0, stream>>>(w_out, wout_bf, DIM_ * DIM_);

    // 1) QKV projection v3: 128x192x64 tiles, 2 blocks/CU, dbuf+prefetch
    {
        dim3 grid(E3_ / 192, M / 128);   // (16, 64) = 1024 blocks
        gemm_qkv<<<grid, 256, 0, stream>>>(x_bf, wqkv_bf, qkv_bf, vT);
    }
    // 2) attention v11: 4-wave blocks, 32 q/wave, 4 blocks/CU
    {
        dim3 grid(N_ / 128, B_ * H_);    // (16, 64) = 1024 blocks
        attn_mfma<<<grid, 256, 0, stream>>>(qkv_bf, vT, ao_bf);
    }
    // 3) out projection (bf16 MFMA, fp32 + bias out)
    {
        dim3 grid(DIM_ / 128, M / 128);  // (8, 64) = 512 blocks (%8==0)
        gemm_out<<<grid, 256, 0, stream>>>(ao_bf, wout_bf, b_out,
                                           out, M, DIM_, DIM_);
    }
    (void)in_sizes; (void)n_in; (void)out_size; (void)ws_size;
}

// Round 9
// 251.797 us; speedup vs baseline: 1.2245x; 1.0872x over previous
//
#include <hip/hip_runtime.h>
#include <hip/hip_bf16.h>
#include <math.h>

// Problem constants
#define B_   4
#define N_   2048
#define DIM_ 1024
#define H_   16
#define DH_  64
#define E3_  3072   // 3*H*DH

typedef __attribute__((ext_vector_type(8)))  short s8v;   // 8 bf16 (4 VGPRs)
typedef __attribute__((ext_vector_type(4)))  float f4v;   // 16x16 MFMA accumulator
typedef __attribute__((ext_vector_type(16))) float f16v;  // 32x32 MFMA accumulator

// fast fp32->bf16: round-half-up (adds 0.5 ulp then truncate). 2 VALU ops.
__device__ __forceinline__ unsigned short f2bf_fast(float f) {
    return (unsigned short)((__builtin_bit_cast(unsigned int, f) + 0x8000u) >> 16);
}
// pack two fp32 -> two bf16 in one u32 via v_perm_b32 (3 VALU ops total)
__device__ __forceinline__ unsigned int pkbf(float a, float b) {
    unsigned int ua = __builtin_bit_cast(unsigned int, a) + 0x8000u;
    unsigned int ub = __builtin_bit_cast(unsigned int, b) + 0x8000u;
    return __builtin_amdgcn_perm(ub, ua, 0x07060302);
}
// single-instruction pack: dst.lo = bf16(a), dst.hi = bf16(b)  (RNE)
__device__ __forceinline__ unsigned int cvtpk(float a, float b) {
    unsigned int r;
    asm("v_cvt_pk_bf16_f32 %0, %1, %2" : "=v"(r) : "v"(a), "v"(b));
    return r;
}
// v_permlane32_swap_b32: after execution
//   a' = [a(lanes 0:31) | b(lanes 0:31)],  b' = [a(lanes 32:63) | b(lanes 32:63)]
__device__ __forceinline__ uint2 pl32(unsigned int a, unsigned int b) {
    asm volatile("v_permlane32_swap_b32 %0, %1" : "+v"(a), "+v"(b));
    return make_uint2(a, b);
}

// async global->LDS, 16 B per lane; LDS dest = wave-uniform base + lane*16
__device__ __forceinline__ void gload_lds16(const void* g, void* l) {
    __builtin_amdgcn_global_load_lds(
        (const __attribute__((address_space(1))) unsigned int*)(uintptr_t)g,
        (__attribute__((address_space(3))) unsigned int*)(uintptr_t)l,
        16, 0, 0);
}

// ---------------------------------------------------------------------------
// fused fp32 -> bf16 convert for all three inputs (1 dispatch instead of 3;
// ~70us of the round-6 total was inter-dispatch overhead across 6 launches)
// blocks: [0,8192) x -> x_bf, [8192,11264) w_qkv -> wqkv_bf, rest w_out.
// All sizes are exact multiples of 1024 elements -> no bounds checks.
// ---------------------------------------------------------------------------
__global__ __launch_bounds__(256) void cvt_all(
    const float* __restrict__ x,  const float* __restrict__ wq,
    const float* __restrict__ wo,
    unsigned short* __restrict__ xb, unsigned short* __restrict__ wqb,
    unsigned short* __restrict__ wob)
{
    const int bid = blockIdx.x;
    const float* in; unsigned short* out; int rb;
    if (bid < 8192)       { in = x;  out = xb;  rb = bid; }
    else if (bid < 11264) { in = wq; out = wqb; rb = bid - 8192; }
    else                  { in = wo; out = wob; rb = bid - 11264; }
    const int i = (rb * 256 + threadIdx.x) * 4;
    float4 v = *(const float4*)(in + i);
    uint2 pk;
    pk.x = pkbf(v.x, v.y);
    pk.y = pkbf(v.z, v.w);
    *(uint2*)(out + i) = pk;
}

// ---------------------------------------------------------------------------
// QKV projection GEMM v2 (round 4/6 version, verbatim — v3's 2-blk/CU
// re-tile was ~18us WORSE in the round-8 total decomposition; reverted):
// qkv[8192][3072] = x[8192][1024] @ w_qkv^T. BM=256 x BN=192 x BK=64,
// 512 thr = 8 waves (2M x 4N), wave tile 128x48. Both-sides swizzle
// (chunk ^= row&7) with pre-swizzled global_load_lds source; dbuf; next
// tile's DMA issued before compute. grid (16,32)=512 blocks = 2 rounds.
// Q-third pre-scaled by 0.125*log2(e); V-third redirected to vT[b,h,d,n].
// ---------------------------------------------------------------------------
__global__ __launch_bounds__(512, 1) void gemm_qkv(
    const unsigned short* __restrict__ A,    // x_bf [8192][1024]
    const unsigned short* __restrict__ Bw,   // wqkv_bf [3072][1024]
    unsigned short* __restrict__ Cb,         // qkv bf16 [8192][3072]
    unsigned short* __restrict__ Vt)         // [B*H][64][2048]
{
    __shared__ unsigned short Ls[2][28672];

    const int tid  = threadIdx.x;
    const int w    = tid >> 6;          // 0..7
    const int lane = tid & 63;
    const int quad = lane >> 4;
    const int l15  = lane & 15;
    const int wm   = w & 1;             // M half (128 rows)
    const int wn   = w >> 1;            // N quarter (48 cols)

    const int lin = blockIdx.y * 16 + blockIdx.x;
    const int swz = (lin & 7) * 64 + (lin >> 3);
    const int m0  = (swz >> 4) * 256;
    const int n0  = (swz & 15) * 192;

    const int r8  = lane >> 3;              // 0..7
    const int chk = (lane & 7) ^ r8;        // pre-swizzled source chunk

    f4v acc[8][3];
    #pragma unroll
    for (int i = 0; i < 8; i++)
        #pragma unroll
        for (int j = 0; j < 3; j++) acc[i][j] = (f4v){0.f, 0.f, 0.f, 0.f};

    #pragma unroll
    for (int j = 0; j < 7; j++) {
        const int u = w * 7 + j;
        const unsigned short* src = (u < 32)
            ? A  + (size_t)(m0 + u * 8 + r8) * 1024 + chk * 8
            : Bw + (size_t)(n0 + (u - 32) * 8 + r8) * 1024 + chk * 8;
        gload_lds16(src, &Ls[0][u * 512]);
    }
    __syncthreads();

    for (int t = 0; t < 16; t++) {
        const int cur = t & 1;

        if (t + 1 < 16) {
            const int k0 = (t + 1) * 64;
            #pragma unroll
            for (int j = 0; j < 7; j++) {
                const int u = w * 7 + j;
                const unsigned short* src = (u < 32)
                    ? A  + (size_t)(m0 + u * 8 + r8) * 1024 + k0 + chk * 8
                    : Bw + (size_t)(n0 + (u - 32) * 8 + r8) * 1024 + k0 + chk * 8;
                gload_lds16(src, &Ls[cur ^ 1][u * 512]);
            }
        }

        #pragma unroll
        for (int s = 0; s < 2; s++) {
            s8v af[8], bf[3];
            #pragma unroll
            for (int ms = 0; ms < 8; ms++) {
                const int row = wm * 128 + ms * 16 + l15;
                af[ms] = *(const s8v*)&Ls[cur][row * 64 + (((s * 4 + quad) ^ (l15 & 7)) * 8)];
            }
            #pragma unroll
            for (int ns = 0; ns < 3; ns++) {
                const int row = 256 + wn * 48 + ns * 16 + l15;
                bf[ns] = *(const s8v*)&Ls[cur][row * 64 + (((s * 4 + quad) ^ (l15 & 7)) * 8)];
            }
            __builtin_amdgcn_s_setprio(1);
            #pragma unroll
            for (int ms = 0; ms < 8; ms++)
                #pragma unroll
                for (int ns = 0; ns < 3; ns++)
                    acc[ms][ns] = __builtin_amdgcn_mfma_f32_16x16x32_bf16(
                        af[ms], bf[ns], acc[ms][ns], 0, 0, 0);
            __builtin_amdgcn_s_setprio(0);
        }

        __syncthreads();
    }

    #pragma unroll
    for (int ns = 0; ns < 3; ns++) {
        const int colb = n0 + wn * 48 + ns * 16;   // wave-uniform, 16-aligned
        if (colb < 2048) {
            const float mul = (colb < 1024) ? 0.18033688011112042f : 1.0f;
            #pragma unroll
            for (int ms = 0; ms < 8; ms++)
                #pragma unroll
                for (int r = 0; r < 4; r++) {
                    const int row = m0 + wm * 128 + ms * 16 + quad * 4 + r;
                    Cb[(size_t)row * E3_ + colb + l15] = f2bf_fast(acc[ms][ns][r] * mul);
                }
        } else {
            const int e = colb + l15 - 2048;
            const int hh = e >> 6, d = e & 63;       // wave-uniform head
            #pragma unroll
            for (int ms = 0; ms < 8; ms++) {
                const int row = m0 + wm * 128 + ms * 16 + quad * 4;  // 4-aligned
                const int bb = row >> 11, nn = row & 2047;
                uint2 pk;
                pk.x = pkbf(acc[ms][ns][0], acc[ms][ns][1]);
                pk.y = pkbf(acc[ms][ns][2], acc[ms][ns][3]);
                *(uint2*)&Vt[(((size_t)bb * 16 + hh) * 64 + d) * 2048 + nn] = pk;
            }
        }
    }
}

// ---------------------------------------------------------------------------
// out projection GEMM v2: out[8192][1024] = ao[8192][1024] @ w_out^T + bias.
// Old m97-style version was LDS-read-bound (round-3 profile of the same
// structure: MfmaUtil 27, 8 b128 per 16 MFMA). This re-tiles to the v3
// skeleton (PASSED round 8): BM=128 x BN=128 x BK=64, 256 thr = 4 waves
// (2x2), wave tile 64x64 = 4x4 MFMAs x 2 k-steps -> 8 b128 per 16 MFMA at
// BK=64 with single barrier/tile. 64 KB LDS -> 2 blocks/CU.
// Both-sides swizzle, dbuf, DMA-before-compute. grid (8,64)=512 (%8==0).
// ---------------------------------------------------------------------------
__global__ __launch_bounds__(256, 2) void gemm_out(
    const unsigned short* __restrict__ A,    // ao_bf [8192][1024]
    const unsigned short* __restrict__ Bw,   // wout_bf [1024][1024]
    const float* __restrict__ bias,
    float* __restrict__ Cf)                  // out fp32 [8192][1024]
{
    // [buf][(128 A-rows + 128 B-rows) * 64 el] = 2 x 32 KB
    __shared__ unsigned short Ls[2][16384];

    const int tid  = threadIdx.x;
    const int w    = tid >> 6;          // 0..3
    const int lane = tid & 63;
    const int quad = lane >> 4;
    const int l15  = lane & 15;
    const int wm   = w & 1;             // M half (64 rows)
    const int wn   = w >> 1;            // N half (64 cols)

    // XCD-chunked swizzle: 512 blocks -> 64 per XCD
    const int lin = blockIdx.y * 8 + blockIdx.x;
    const int swz = (lin & 7) * 64 + (lin >> 3);
    const int m0  = (swz >> 3) * 128;
    const int n0  = (swz & 7) * 128;

    // staging: 32 units of 1 KB (8 rows x 64 el); wave w stages units
    // w*8..w*8+7. Lane: row = unit*8 + (lane>>3), source chunk pre-swizzled.
    const int r8  = lane >> 3;              // 0..7
    const int chk = (lane & 7) ^ r8;        // pre-swizzled source chunk

    f4v acc[4][4];
    #pragma unroll
    for (int i = 0; i < 4; i++)
        #pragma unroll
        for (int j = 0; j < 4; j++) acc[i][j] = (f4v){0.f, 0.f, 0.f, 0.f};

    // ---- prologue: stage tile 0 into buffer 0 ----
    #pragma unroll
    for (int j = 0; j < 8; j++) {
        const int u = w * 8 + j;
        const unsigned short* src = (u < 16)
            ? A  + (size_t)(m0 + u * 8 + r8) * 1024 + chk * 8
            : Bw + (size_t)(n0 + (u - 16) * 8 + r8) * 1024 + chk * 8;
        gload_lds16(src, &Ls[0][u * 512]);
    }
    __syncthreads();

    for (int t = 0; t < 16; t++) {
        const int cur = t & 1;

        // ---- issue next tile's DMA first (latency hidden by compute) ----
        if (t + 1 < 16) {
            const int k0 = (t + 1) * 64;
            #pragma unroll
            for (int j = 0; j < 8; j++) {
                const int u = w * 8 + j;
                const unsigned short* src = (u < 16)
                    ? A  + (size_t)(m0 + u * 8 + r8) * 1024 + k0 + chk * 8
                    : Bw + (size_t)(n0 + (u - 16) * 8 + r8) * 1024 + k0 + chk * 8;
                gload_lds16(src, &Ls[cur ^ 1][u * 512]);
            }
        }

        // ---- compute on current buffer: 2 k-steps x (4x4) MFMAs ----
        #pragma unroll
        for (int s = 0; s < 2; s++) {
            s8v af[4], bf[4];
            #pragma unroll
            for (int ms = 0; ms < 4; ms++) {
                const int row = wm * 64 + ms * 16 + l15;
                af[ms] = *(const s8v*)&Ls[cur][row * 64 + (((s * 4 + quad) ^ (l15 & 7)) * 8)];
            }
            #pragma unroll
            for (int ns = 0; ns < 4; ns++) {
                const int row = 128 + wn * 64 + ns * 16 + l15;
                bf[ns] = *(const s8v*)&Ls[cur][row * 64 + (((s * 4 + quad) ^ (l15 & 7)) * 8)];
            }
            __builtin_amdgcn_s_setprio(1);
            #pragma unroll
            for (int ms = 0; ms < 4; ms++)
                #pragma unroll
                for (int ns = 0; ns < 4; ns++)
                    acc[ms][ns] = __builtin_amdgcn_mfma_f32_16x16x32_bf16(
                        af[ms], bf[ns], acc[ms][ns], 0, 0, 0);
            __builtin_amdgcn_s_setprio(0);
        }

        __syncthreads();
    }

    // ---- epilogue: fp32 + bias (old gemm_out epilogue, verbatim) ----
    #pragma unroll
    for (int ns = 0; ns < 4; ns++) {
        const float bz = bias[n0 + wn * 64 + ns * 16 + l15];
        #pragma unroll
        for (int ms = 0; ms < 4; ms++)
            #pragma unroll
            for (int r = 0; r < 4; r++) {
                const int row = m0 + wm * 64 + ms * 16 + quad * 4 + r;
                Cf[(size_t)row * 1024 + n0 + wn * 64 + ns * 16 + l15] =
                    acc[ms][ns][r] + bz;
            }
    }
}

// ---------------------------------------------------------------------------
// MFMA flash attention v7 (round 3/4 version, verbatim — measured 80us,
// best of all structural variants; v9/v10/v11 all regressed. The attn wall
// is SIMD issue-port saturation: MfmaUtil 49 + VALU 44 + ds_read/trans
// issue ~ 100%. 32x32x16, in-register P, 8 waves x 32 q-rows, DMA-staged
// swizzled K/V, dbuf, one barrier per tile, lc-MFMA denominator.)
// qkv bf16 [m][3072] (Q pre-scaled by 0.125*log2e); vT[b*16+h][d][n] bf16.
// ---------------------------------------------------------------------------
__global__ __launch_bounds__(512, 4) void attn_mfma(
    const unsigned short* __restrict__ qkv,
    const unsigned short* __restrict__ vT,
    unsigned short* __restrict__ ao)
{
    __shared__ __align__(16) unsigned short Ks[2][64][64];   // [buf][key][d] swz
    __shared__ __align__(16) unsigned short Vs[2][64][64];   // [buf][d][key] swz

    const int tid  = threadIdx.x;
    const int w    = tid >> 6;          // 0..7
    const int lane = tid & 63;
    const int l31  = lane & 31;
    const int hi5  = lane >> 5;         // 0/1
    const int h8   = hi5 * 8;

    // XCD-chunked swizzle over the 512-block grid (8 x-tiles fastest)
    const int lin = blockIdx.y * 8 + blockIdx.x;
    const int swz = (lin & 7) * 64 + (lin >> 3);
    const int bx  = swz & 7;
    const int bh  = swz >> 3;
    const int b   = bh >> 4;
    const int h   = bh & 15;
    const int q0  = bx * 256;           // 256 q-rows per block
    const int qb  = q0 + w * 32;        // 32 q-rows per wave

    const unsigned short* qp  = qkv + (size_t)b * N_ * E3_ + (size_t)h * DH_;
    const unsigned short* kp  = qp + 1024;
    const unsigned short* vtp = vT + (size_t)bh * 64 * 2048;

    // DMA staging: wave w stages rows w*8..w*8+7 of K and V (1024 B each).
    // LDS dest linear; global source chunk pre-swizzled: chunk ^= row&7.
    const int drow = lane >> 3;             // 0..7 within slice
    const int dchk = (lane & 7) ^ drow;     // pre-swizzled source chunk
    const int grow = w * 8 + drow;          // row 0..63 (grow&7 == drow)

    // Q B-fragments straight from global (one-time): B[k=d][col=qrow]
    s8v bq[4];
    {
        const unsigned short* qrow = qp + (size_t)(qb + l31) * E3_;
        #pragma unroll
        for (int ks = 0; ks < 4; ks++)
            bq[ks] = *(const s8v*)(qrow + ks * 16 + h8);
    }

    // ones B-fragment (bf16 1.0) for row-sum MFMA
    s8v ones;
    #pragma unroll
    for (int i = 0; i < 8; i++) ones[i] = (short)0x3F80;

    const f16v fzero = {0.f,0.f,0.f,0.f,0.f,0.f,0.f,0.f,
                        0.f,0.f,0.f,0.f,0.f,0.f,0.f,0.f};
    f16v o0 = fzero, o1 = fzero;   // d = 0..31 / 32..63
    f16v lc = fzero;               // row-sums, layout-matched to o

    // ---- prologue: DMA tile 0 into buffer 0 ----
    gload_lds16(kp  + (size_t)grow * E3_  + dchk * 8, &Ks[0][w * 8][0]);
    gload_lds16(vtp + (size_t)grow * 2048 + dchk * 8, &Vs[0][w * 8][0]);
    __syncthreads();   // vmcnt(0) drain + barrier

    for (int kt = 0; kt < N_ / 64; kt++) {
        const int cur = kt & 1;

        // ---- DMA next tile into back buffer (latency hidden by compute) ----
        if (kt + 1 < N_ / 64) {
            const int kn = (kt + 1) * 64;
            gload_lds16(kp  + (size_t)(kn + grow) * E3_  + dchk * 8,
                        &Ks[cur ^ 1][w * 8][0]);
            gload_lds16(vtp + (size_t)grow * 2048 + kn + dchk * 8,
                        &Vs[cur ^ 1][w * 8][0]);
        }

        #pragma unroll
        for (int ksub = 0; ksub < 2; ksub++) {
            // K A-fragments: A[row=key][k=d], row = ksub*32 + l31
            const int krow = ksub * 32 + l31;
            const int ksw  = (l31 & 7) * 8;     // krow&7 == l31&7
            s8v ak[4];
            #pragma unroll
            for (int ks = 0; ks < 4; ks++)
                ak[ks] = *(const s8v*)&Ks[cur][krow][(ks * 16 + h8) ^ ksw];

            // S^T -> exp2 -> in-register P A-fragments
            f16v st = fzero;
            __builtin_amdgcn_s_setprio(1);
            st = __builtin_amdgcn_mfma_f32_32x32x16_bf16(ak[0], bq[0], st, 0, 0, 0);
            st = __builtin_amdgcn_mfma_f32_32x32x16_bf16(ak[1], bq[1], st, 0, 0, 0);
            st = __builtin_amdgcn_mfma_f32_32x32x16_bf16(ak[2], bq[2], st, 0, 0, 0);
            st = __builtin_amdgcn_mfma_f32_32x32x16_bf16(ak[3], bq[3], st, 0, 0, 0);
            __builtin_amdgcn_s_setprio(0);

            float pe[16];
            #pragma unroll
            for (int i = 0; i < 16; i++)
                pe[i] = __builtin_amdgcn_exp2f(st[i]);

            // pack pairs, swap halves: lane gets its q-row's keys
            s8v pa[2];
            {
                union { s8v v; unsigned int u[4]; } f0, f1;
                uint2 r;
                r = pl32(cvtpk(pe[0],  pe[1]),  cvtpk(pe[4],  pe[5]));
                f0.u[0] = r.x; f0.u[2] = r.y;
                r = pl32(cvtpk(pe[2],  pe[3]),  cvtpk(pe[6],  pe[7]));
                f0.u[1] = r.x; f0.u[3] = r.y;
                r = pl32(cvtpk(pe[8],  pe[9]),  cvtpk(pe[12], pe[13]));
                f1.u[0] = r.x; f1.u[2] = r.y;
                r = pl32(cvtpk(pe[10], pe[11]), cvtpk(pe[14], pe[15]));
                f1.u[1] = r.x; f1.u[3] = r.y;
                pa[0] = f0.v;   // keys ksub*32 + 0..15
                pa[1] = f1.v;   // keys ksub*32 + 16..31
            }

            // ---- O += P V ; l += P @ ones ----
            #pragma unroll
            for (int j = 0; j < 2; j++) {
                const int kbase = (ksub * 2 + j) * 16 + h8;
                const int vsw   = (l31 & 7) * 8;
                s8v bv0 = *(const s8v*)&Vs[cur][l31     ][kbase ^ vsw];
                s8v bv1 = *(const s8v*)&Vs[cur][32 + l31][kbase ^ vsw];
                __builtin_amdgcn_s_setprio(1);
                o0 = __builtin_amdgcn_mfma_f32_32x32x16_bf16(pa[j], bv0, o0, 0, 0, 0);
                o1 = __builtin_amdgcn_mfma_f32_32x32x16_bf16(pa[j], bv1, o1, 0, 0, 0);
                lc = __builtin_amdgcn_mfma_f32_32x32x16_bf16(pa[j], ones, lc, 0, 0, 0);
                __builtin_amdgcn_s_setprio(0);
            }
        }

        __syncthreads();
    }

    // normalize + write ao bf16 [m][1024]; lc layout == o layout
    {
        float inv[16];
        #pragma unroll
        for (int r = 0; r < 16; r++) inv[r] = 1.f / lc[r];
        #pragma unroll
        for (int r = 0; r < 16; r++) {
            const int qrow = qb + (r & 3) + 8 * (r >> 2) + 4 * hi5;
            const size_t base = ((size_t)b * N_ + qrow) * (H_ * DH_) + h * DH_;
            ao[base + l31]      = f2bf_fast(o0[r] * inv[r]);
            ao[base + 32 + l31] = f2bf_fast(o1[r] * inv[r]);
        }
    }
}

// ---------------------------------------------------------------------------
// Launch — 4 dispatches (was 6)
// ---------------------------------------------------------------------------
extern "C" void kernel_launch(void* const* d_in, const int* in_sizes, int n_in,
                              void* d_out, int out_size, void* d_ws, size_t ws_size,
                              hipStream_t stream) {
    const float* x     = (const float*)d_in[0];   // [B,N,DIM]
    const float* w_qkv = (const float*)d_in[1];   // [3072, 1024]
    const float* w_out = (const float*)d_in[2];   // [1024, 1024]
    const float* b_out = (const float*)d_in[3];   // [1024]
    float* out = (float*)d_out;                   // [B,N,DIM] fp32

    char* ws = (char*)d_ws;
    unsigned short* x_bf    = (unsigned short*)(ws);                        // 16 MB
    unsigned short* wqkv_bf = (unsigned short*)(ws + (((size_t)16) << 20)); //  6 MB
    unsigned short* wout_bf = (unsigned short*)(ws + (((size_t)22) << 20)); //  2 MB
    unsigned short* qkv_bf  = (unsigned short*)(ws + (((size_t)24) << 20)); // 48 MB
    unsigned short* vT      = (unsigned short*)(ws + (((size_t)72) << 20)); // 16 MB
    unsigned short* ao_bf   = (unsigned short*)(ws + (((size_t)88) << 20)); // 16 MB

    const int M = B_ * N_;   // 8192

    // 0) fused input conversions fp32 -> bf16 (1 dispatch)
    cvt_all<<<12288, 256, 0, stream>>>(x, w_qkv, w_out, x_bf, wqkv_bf, wout_bf);

    // 1) QKV projection v2: 256x192x64 tiles, dbuf+prefetch, swizzled LDS
    {
        dim3 grid(E3_ / 192, M / 256);   // (16, 32) = 512 blocks
        gemm_qkv<<<grid, 512, 0, stream>>>(x_bf, wqkv_bf, qkv_bf, vT);
    }
    // 2) attention v7: 8 waves x 32 q-rows, 2 blocks/CU (proven 80us)
    {
        dim3 grid(N_ / 256, B_ * H_);    // (8, 64) = 512 blocks
        attn_mfma<<<grid, 512, 0, stream>>>(qkv_bf, vT, ao_bf);
    }
    // 3) out projection v2: 128x128x64 tiles, 2 blocks/CU, dbuf+prefetch
    {
        dim3 grid(DIM_ / 128, M / 128);  // (8, 64) = 512 blocks (%8==0)
        gemm_out<<<grid, 256, 0, stream>>>(ao_bf, wout_bf, b_out, out);
    }
    (void)in_sizes; (void)n_in; (void)out_size; (void)ws_size;
}